// Round 15
// baseline (20.558 us; speedup 1.0000x reference)
//
#include <hip/hip_runtime.h>
#include <math.h>

#define NR 256   // rules
#define NF 128   // features
#define BCOLS 64 // batch columns per block (2 MFMA B-tiles) -- r15: was 32

typedef short  s16x8  __attribute__((ext_vector_type(8)));   // 8 bf16 bit patterns
typedef __bf16 bf16x8 __attribute__((ext_vector_type(8)));
typedef float  f32x16 __attribute__((ext_vector_type(16)));  // MFMA 32x32 acc

__device__ __forceinline__ unsigned short f2bf(float x) {
    unsigned int u = __float_as_uint(x);
    unsigned int r = (u + 0x7FFFu + ((u >> 16) & 1u)) >> 16;  // RNE
    return (unsigned short)r;
}
__device__ __forceinline__ float bf2f(unsigned short b) {
    return __uint_as_float(((unsigned int)b) << 16);
}
__device__ __forceinline__ bf16x8 as_bf(s16x8 v) {
    return __builtin_bit_cast(bf16x8, v);
}
__device__ __forceinline__ f32x16 mfma_bf16(s16x8 a, s16x8 b, f32x16 acc) {
    return __builtin_amdgcn_mfma_f32_32x32x16_bf16(as_bf(a), as_bf(b), acc, 0, 0, 0);
}

// ---------------------------------------------------------------------------
// prep2 (verbatim r9/r13, validated): parallel + coalesced-store prep.
// ---------------------------------------------------------------------------
__global__ __launch_bounds__(256) void prep2_kernel(
    const float* __restrict__ mu, const float* __restrict__ sigma,
    const float* __restrict__ w3,
    unsigned short* __restrict__ PH, unsigned short* __restrict__ PL,
    unsigned short* __restrict__ WC,
    float* __restrict__ Cr, float* __restrict__ W0)
{
    const int blk = blockIdx.x;
    if (blk < 32) {
        const int t    = blk * 256 + threadIdx.x;   // 0..8191
        const int e    = t >> 6;                     // entry 0..127
        const int lane = t & 63;
        const int rt   = e >> 4;
        const int ks2  = e & 15;
        const bool second = (ks2 >= 8);
        const int fb   = (ks2 & 7) * 16 + (lane >> 5) * 8;
        const int rule = rt * 32 + (lane & 31);

        const float* mrow = mu    + (size_t)rule * NF + fb;
        const float* srow = sigma + (size_t)rule * NF + fb;
        const float* wrow = w3    + (size_t)rule * (NF + 1) + 1 + fb;

        s16x8 vh, vl, vw;
        #pragma unroll
        for (int j = 0; j < 8; ++j) {
            const float s  = srow[j];
            const float m  = mrow[j];
            const float w  = wrow[j];
            const float u2 = -0.5f / fmaxf(s * s, 1e-30f);
            const float val = second ? (-2.0f * u2 * m) : u2;
            const unsigned short hh = f2bf(val);
            vh[j] = (short)hh;
            vl[j] = (short)f2bf(val - bf2f(hh));
            const unsigned short wh = f2bf(w);
            vw[j] = (short)(second ? f2bf(w - bf2f(wh)) : wh);
        }
        ((s16x8*)PH)[t] = vh;   // t == e*64 + lane : fully coalesced 16B
        ((s16x8*)PL)[t] = vl;
        ((s16x8*)WC)[t] = vw;
    } else {
        const int rg   = blk - 32;                  // rule group of 32
        const int rl   = threadIdx.x >> 3;
        const int jj   = threadIdx.x & 7;
        const int rule = rg * 32 + rl;
        const float* mrow = mu    + (size_t)rule * NF + jj * 16;
        const float* srow = sigma + (size_t)rule * NF + jj * 16;
        float cc = 0.f;
        #pragma unroll
        for (int q = 0; q < 16; q += 4) {
            const float4 s4 = *(const float4*)(srow + q);
            const float4 m4 = *(const float4*)(mrow + q);
            cc += (-0.5f / fmaxf(s4.x * s4.x, 1e-30f)) * m4.x * m4.x;
            cc += (-0.5f / fmaxf(s4.y * s4.y, 1e-30f)) * m4.y * m4.y;
            cc += (-0.5f / fmaxf(s4.z * s4.z, 1e-30f)) * m4.z * m4.z;
            cc += (-0.5f / fmaxf(s4.w * s4.w, 1e-30f)) * m4.w * m4.w;
        }
        cc += __shfl_down(cc, 4);
        cc += __shfl_down(cc, 2);
        cc += __shfl_down(cc, 1);
        if (jj == 0) {
            Cr[rule] = cc;
            W0[rule] = w3[(size_t)rule * (NF + 1)];
        }
    }
}

// ---------------------------------------------------------------------------
// main v4 (r15): r8's K-loop VERBATIM in structure, but each block now covers
// 64 batch cols (two 32-col B-tiles per wave) -> grid halves to 128 blocks ->
// chip-wide A-param traffic halves (98 -> 49 MB). Tests the r14 post-mortem
// theory that main is chip-wide-BW-bound on the A stream (per-block pipeline
// depth was proven irrelevant). Per-column math bit-identical to r8.
//   S = PH.bh (accS0t) + PL.bh + PH.bl (accS1t) ; Q per tile (accQt)
// C/D layout (HW-verified): col=lane&31, row=(reg&3)+8*(reg>>2)+4*(lane>>5)
// ---------------------------------------------------------------------------
__global__ __launch_bounds__(512) void fnn_mfma(
    const float* __restrict__ data,
    const unsigned short* __restrict__ PH, const unsigned short* __restrict__ PL,
    const unsigned short* __restrict__ WC,
    const float* __restrict__ Cr, const float* __restrict__ W0,
    float* __restrict__ out)
{
    __shared__ s16x8 sBH[16][128], sBL[16][128];   // 64 KB (two 32-col tiles)
    __shared__ float sCr[NR], sW0[NR];
    __shared__ float redD[8][BCOLS], redN[8][BCOLS];

    const int tid = threadIdx.x;
    if (tid < NR) sCr[tid] = Cr[tid];
    else          sW0[tid - NR] = W0[tid - NR];

    const int b0 = blockIdx.x * BCOLS;

    // ---- cooperative B build: thread (bks,bln) -> 8 LDS entries (2 tiles)
    {
        const int bks = tid >> 6;        // 0..7
        const int bln = tid & 63;
        #pragma unroll
        for (int tile = 0; tile < 2; ++tile) {
            const float* p = data + (size_t)(b0 + tile * 32 + (bln & 31)) * NF
                                  + bks * 16 + (bln >> 5) * 8;
            const float4 v0 = *(const float4*)(p);
            const float4 v1 = *(const float4*)(p + 4);
            const float dv[8] = {v0.x, v0.y, v0.z, v0.w, v1.x, v1.y, v1.z, v1.w};
            s16x8 e_d, e_dl, e_d2, e_d2l;
            #pragma unroll
            for (int j = 0; j < 8; ++j) {
                const float d  = dv[j];
                const float d2 = d * d;
                const unsigned short dh  = f2bf(d);
                const unsigned short d2h = f2bf(d2);
                e_d  [j] = (short)dh;
                e_dl [j] = (short)f2bf(d  - bf2f(dh));
                e_d2 [j] = (short)d2h;
                e_d2l[j] = (short)f2bf(d2 - bf2f(d2h));
            }
            const int o = tile * 64 + bln;
            sBH[bks    ][o] = e_d2;   // ks<8  : d^2 hi
            sBL[bks    ][o] = e_d2l;  // ks<8  : d^2 lo
            sBH[bks + 8][o] = e_d;    // ks>=8 : d hi
            sBL[bks + 8][o] = e_dl;   // ks>=8 : d lo
        }
    }
    __syncthreads();

    const int wv   = tid >> 6;     // wave id == rule tile
    const int lane = tid & 63;
    const int col  = lane & 31;
    const int half = lane >> 5;

    const s16x8* PHp = (const s16x8*)PH + (size_t)wv * 16 * 64 + lane;
    const s16x8* PLp = (const s16x8*)PL + (size_t)wv * 16 * 64 + lane;
    const s16x8* WCp = (const s16x8*)WC + (size_t)wv * 16 * 64 + lane;

    f32x16 accS0a, accS1a, accQa, accS0b, accS1b, accQb;
    #pragma unroll
    for (int e = 0; e < 16; ++e) {
        accS0a[e] = 0.f; accS1a[e] = 0.f; accQa[e] = 0.f;
        accS0b[e] = 0.f; accS1b[e] = 0.f; accQb[e] = 0.f;
    }

    s16x8 a0 = PHp[0], a1 = PLp[0], a2 = WCp[0];
    #pragma unroll 1
    for (int ks = 0; ks < 16; ++ks) {
        // strict 1-deep prefetch (clamped index keeps it branchless & bounded)
        const int nofs = ((ks < 15) ? (ks + 1) : ks) * 64;
        const s16x8 n0 = PHp[nofs];
        const s16x8 n1 = PLp[nofs];
        const s16x8 n2 = WCp[nofs];

        const s16x8 bh0 = sBH[ks][lane];
        const s16x8 bl0 = sBL[ks][lane];
        const s16x8 bh1 = sBH[ks][64 + lane];
        const s16x8 bl1 = sBL[ks][64 + lane];
        accS0a = mfma_bf16(a0, bh0, accS0a);   // PH . {d2h|dh}  tile0
        accS1a = mfma_bf16(a1, bh0, accS1a);   // PL . {d2h|dh}
        accS1a = mfma_bf16(a0, bl0, accS1a);   // PH . {d2l|dl}
        accS0b = mfma_bf16(a0, bh1, accS0b);   // tile1
        accS1b = mfma_bf16(a1, bh1, accS1b);
        accS1b = mfma_bf16(a0, bl1, accS1b);
        if (ks < 8) {                           // uniform branch
            accQa = mfma_bf16(a2, sBH[ks + 8][lane], accQa);       // w_hi.dh t0
            accQa = mfma_bf16(a2, sBL[ks + 8][lane], accQa);       // w_hi.dl t0
            accQb = mfma_bf16(a2, sBH[ks + 8][64 + lane], accQb);  // t1
            accQb = mfma_bf16(a2, sBL[ks + 8][64 + lane], accQb);
        } else {
            accQa = mfma_bf16(a2, bh0, accQa);                     // w_lo.dh
            accQb = mfma_bf16(a2, bh1, accQb);
        }
        a0 = n0; a1 = n1; a2 = n2;
    }

    float denA = 0.f, numA = 0.f, denB = 0.f, numB = 0.f;
    #pragma unroll
    for (int reg = 0; reg < 16; ++reg) {
        const int rloc = (reg & 3) + 8 * (reg >> 2) + 4 * half;
        const int rule = wv * 32 + rloc;
        const float cr = sCr[rule];
        const float w0 = sW0[rule];
        const float Sa  = accS0a[reg] + accS1a[reg] + cr;
        const float rva = __expf(fminf(Sa, 0.f)) - 28.0f;   // RULE_OFFSET (10^-18==-28)
        denA += rva;
        numA += rva * (accQa[reg] + w0);
        const float Sb  = accS0b[reg] + accS1b[reg] + cr;
        const float rvb = __expf(fminf(Sb, 0.f)) - 28.0f;
        denB += rvb;
        numB += rvb * (accQb[reg] + w0);
    }
    denA += __shfl_xor(denA, 32);
    numA += __shfl_xor(numA, 32);
    denB += __shfl_xor(denB, 32);
    numB += __shfl_xor(numB, 32);
    if (half == 0) {
        redD[wv][col]      = denA;  redN[wv][col]      = numA;
        redD[wv][32 + col] = denB;  redN[wv][32 + col] = numB;
    }
    __syncthreads();

    if (tid < BCOLS) {
        float den = 0.f, num = 0.f;
        #pragma unroll
        for (int w = 0; w < 8; ++w) { den += redD[w][tid]; num += redN[w][tid]; }
        out[b0 + tid] = 1.0f / (1.0f + __expf(-(num / den)));
    }
}

// ---------------------------------------------------------------------------
// fallback (ws too small): fused f32 version (round-2 structure, known-good).
// ---------------------------------------------------------------------------
#define TBF 8
__global__ __launch_bounds__(256) void fnn_fused(
    const float* __restrict__ data,
    const float* __restrict__ mu, const float* __restrict__ sigma,
    const float* __restrict__ w3,
    float* __restrict__ out)
{
    __shared__ float d_tile[TBF][NF];
    __shared__ float red[TBF][2][4];

    const int tid = threadIdx.x;
    const int b0  = blockIdx.x * TBF;
    {
        const float4* src = (const float4*)(data + (size_t)b0 * NF);
        ((float4*)(&d_tile[0][0]))[tid] = src[tid];
    }
    __syncthreads();

    const float* mu_r = mu    + (size_t)tid * NF;
    const float* sg_r = sigma + (size_t)tid * NF;
    const float* w_r  = w3    + (size_t)tid * (NF + 1);

    float S[TBF], Q[TBF];
    #pragma unroll
    for (int b = 0; b < TBF; ++b) { S[b] = 0.f; Q[b] = 0.f; }

    #pragma unroll 2
    for (int f = 0; f < NF; f += 4) {
        const float4 m4 = *(const float4*)(mu_r + f);
        const float4 s4 = *(const float4*)(sg_r + f);
        const float w0 = w_r[1 + f + 0], w1 = w_r[1 + f + 1];
        const float w2 = w_r[1 + f + 2], w3v = w_r[1 + f + 3];
        float4 c4;
        c4.x = -0.5f / fmaxf(s4.x * s4.x, 1e-30f);
        c4.y = -0.5f / fmaxf(s4.y * s4.y, 1e-30f);
        c4.z = -0.5f / fmaxf(s4.z * s4.z, 1e-30f);
        c4.w = -0.5f / fmaxf(s4.w * s4.w, 1e-30f);
        #pragma unroll
        for (int b = 0; b < TBF; ++b) {
            const float4 d4 = *(const float4*)(&d_tile[b][f]);
            float t;
            t = d4.x - m4.x; S[b] = fmaf(t * t, c4.x, S[b]); Q[b] = fmaf(d4.x, w0,  Q[b]);
            t = d4.y - m4.y; S[b] = fmaf(t * t, c4.y, S[b]); Q[b] = fmaf(d4.y, w1,  Q[b]);
            t = d4.z - m4.z; S[b] = fmaf(t * t, c4.z, S[b]); Q[b] = fmaf(d4.z, w2,  Q[b]);
            t = d4.w - m4.w; S[b] = fmaf(t * t, c4.w, S[b]); Q[b] = fmaf(d4.w, w3v, Q[b]);
        }
    }

    const float bias = w_r[0];
    #pragma unroll
    for (int b = 0; b < TBF; ++b) {
        float rule = __expf(S[b]) - 28.0f;
        float rc   = rule * (bias + Q[b]);
        #pragma unroll
        for (int off = 32; off > 0; off >>= 1) {
            rule += __shfl_down(rule, off);
            rc   += __shfl_down(rc,   off);
        }
        if ((tid & 63) == 0) {
            red[b][0][tid >> 6] = rule;
            red[b][1][tid >> 6] = rc;
        }
    }
    __syncthreads();
    if (tid < TBF) {
        const float den = red[tid][0][0] + red[tid][0][1] + red[tid][0][2] + red[tid][0][3];
        const float num = red[tid][1][0] + red[tid][1][1] + red[tid][1][2] + red[tid][1][3];
        out[b0 + tid] = 1.0f / (1.0f + __expf(-(num / den)));
    }
}

extern "C" void kernel_launch(void* const* d_in, const int* in_sizes, int n_in,
                              void* d_out, int out_size, void* d_ws, size_t ws_size,
                              hipStream_t stream) {
    const float* data  = (const float*)d_in[0];
    const float* mu    = (const float*)d_in[1];
    const float* sigma = (const float*)d_in[2];
    const float* w3    = (const float*)d_in[3];
    float* out = (float*)d_out;

    const int batch = in_sizes[0] / NF;   // 8192
    // PH + PL + WC (3 x 64K bf16 = 3 x 128 KiB) + Cr + W0 = 395,264 B
    const size_t need = 3u * 65536u * sizeof(unsigned short) + 2u * NR * sizeof(float);

    if (ws_size >= need && (batch % BCOLS) == 0) {
        unsigned short* PH = (unsigned short*)d_ws;
        unsigned short* PL = PH + 65536;
        unsigned short* WC = PL + 65536;
        float* Cr = (float*)(WC + 65536);
        float* W0 = Cr + NR;
        prep2_kernel<<<40, 256, 0, stream>>>(mu, sigma, w3, PH, PL, WC, Cr, W0);
        fnn_mfma<<<batch / BCOLS, 512, 0, stream>>>(data, PH, PL, WC, Cr, W0, out);
    } else {
        fnn_fused<<<batch / TBF, 256, 0, stream>>>(data, mu, sigma, w3, out);
    }
}